// Round 7
// baseline (255.992 us; speedup 1.0000x reference)
//
#include <hip/hip_runtime.h>
#include <cfloat>

#define BB 32
#define NN 2048
#define DD 128
#define RM 128    // rows per block (4 waves x 32 rows/wave)
#define CN 64     // cols per tile

typedef __attribute__((ext_vector_type(8))) short short8;
typedef __attribute__((ext_vector_type(4))) float float4v;

__device__ __forceinline__ unsigned short f2bf(float f) {
    unsigned int u = __builtin_bit_cast(unsigned int, f);
    u += 0x7FFFu + ((u >> 16) & 1u);   // RNE
    return (unsigned short)(u >> 16);
}

__device__ __forceinline__ unsigned int umn(unsigned int a, unsigned int b) { return a < b ? a : b; }
__device__ __forceinline__ unsigned int umx(unsigned int a, unsigned int b) { return a > b ? a : b; }
#define CSU(a, b) { unsigned int _lo = umn(a, b), _hi = umx(a, b); (a) = _lo; (b) = _hi; }

// async global->LDS, 16B per lane. LDS dest is wave-uniform base + lane*16.
__device__ __forceinline__ void gl2lds16(const unsigned short* g, unsigned short* l) {
    __builtin_amdgcn_global_load_lds(
        (const __attribute__((address_space(1))) void*)g,
        (__attribute__((address_space(3))) void*)l, 16, 0, 0);
}

// fused: sq = sum(x^2) per row, and bf16 copy of x into workspace
__global__ __launch_bounds__(256) void prep_kernel(const float* __restrict__ x,
        unsigned short* __restrict__ xb16, float* __restrict__ sq) {
    int t = blockIdx.x * 256 + threadIdx.x;
    int row = t >> 2;
    int q = t & 3;
    const float4* xp = reinterpret_cast<const float4*>(x + (size_t)row * DD + q * 32);
    unsigned short* op = xb16 + (size_t)row * DD + q * 32;
    float acc = 0.f;
#pragma unroll
    for (int i = 0; i < 4; ++i) {
        float4 v0 = xp[2 * i], v1 = xp[2 * i + 1];
        acc += v0.x * v0.x + v0.y * v0.y + v0.z * v0.z + v0.w * v0.w;
        acc += v1.x * v1.x + v1.y * v1.y + v1.z * v1.z + v1.w * v1.w;
        short8 pk;
        pk[0] = (short)f2bf(v0.x); pk[1] = (short)f2bf(v0.y);
        pk[2] = (short)f2bf(v0.z); pk[3] = (short)f2bf(v0.w);
        pk[4] = (short)f2bf(v1.x); pk[5] = (short)f2bf(v1.y);
        pk[6] = (short)f2bf(v1.z); pk[7] = (short)f2bf(v1.w);
        *reinterpret_cast<short8*>(op + i * 8) = pk;
    }
    acc += __shfl_xor(acc, 1);
    acc += __shfl_xor(acc, 2);
    if (q == 0) sq[row] = acc;
}

__global__ __launch_bounds__(256) void sq_kernel(const float* __restrict__ x,
                                                 float* __restrict__ sq) {
    int t = blockIdx.x * 256 + threadIdx.x;
    int row = t >> 2;
    int q = t & 3;
    const float4* xp = reinterpret_cast<const float4*>(x + (size_t)row * DD + q * 32);
    float acc = 0.f;
#pragma unroll
    for (int i = 0; i < 8; ++i) {
        float4 v = xp[i];
        acc += v.x * v.x + v.y * v.y + v.z * v.z + v.w * v.w;
    }
    acc += __shfl_xor(acc, 1);
    acc += __shfl_xor(acc, 2);
    if (q == 0) sq[row] = acc;
}

// Main: per (batch, row-block of 128, column-half) -> per-row top-8 packed keys.
// B tile layout: row r (0..63), 16 chunks of 8 bf16; chunk c at pos c^(r&7).
template<bool PRE>
__global__ __launch_bounds__(256, 4) void knn_main(const float* __restrict__ x,
        const unsigned short* __restrict__ xb16g,
        const float* __restrict__ sqv,
        unsigned int* __restrict__ top8, int halves) {
    __shared__ __align__(16) unsigned short btile[2 * CN * DD]; // 32 KB dbuf => 4 blocks/CU

    const int b = blockIdx.x;            // flat%8 = b%8: batch pinned to an XCD
    const int row0 = blockIdx.y * RM;
    const int h = blockIdx.z;
    const int colspan = NN / halves;
    const int col0 = h * colspan;
    const int tiles = colspan / CN;
    const int tid = threadIdx.x;
    const int w = tid >> 6;
    const int lane = tid & 63;
    const int m = lane & 15;
    const int quad = lane >> 4;
    const float* __restrict__ xb = x + (size_t)b * NN * DD;
    const unsigned short* __restrict__ gb = PRE ? xb16g + (size_t)b * NN * DD : nullptr;

    // ---- A fragments direct from global: 2 row-groups x 4 k-chunks per lane ----
    short8 afrag[2][4];
    if constexpr (PRE) {
#pragma unroll
        for (int rg = 0; rg < 2; ++rg)
#pragma unroll
            for (int kc = 0; kc < 4; ++kc)
                afrag[rg][kc] = *reinterpret_cast<const short8*>(
                    gb + (size_t)(row0 + 32 * w + rg * 16 + m) * DD + kc * 32 + quad * 8);
    } else {
#pragma unroll
        for (int rg = 0; rg < 2; ++rg)
#pragma unroll
            for (int kc = 0; kc < 4; ++kc) {
                const float4* src = reinterpret_cast<const float4*>(
                    xb + (size_t)(row0 + 32 * w + rg * 16 + m) * DD + kc * 32 + quad * 8);
                float4 v0 = src[0], v1 = src[1];
                short8 pk;
                pk[0] = (short)f2bf(v0.x); pk[1] = (short)f2bf(v0.y);
                pk[2] = (short)f2bf(v0.z); pk[3] = (short)f2bf(v0.w);
                pk[4] = (short)f2bf(v1.x); pk[5] = (short)f2bf(v1.y);
                pk[6] = (short)f2bf(v1.z); pk[7] = (short)f2bf(v1.w);
                afrag[rg][kc] = pk;
            }
    }

    // ---- stage tile 0 ----
    {
        unsigned short* buf = btile;
        if constexpr (PRE) {
#pragma unroll
            for (int l = 0; l < 4; ++l) {
                int f = (l * 4 + w) * 64 + lane;
                int r = f >> 4, p = f & 15;
                int c = p ^ (r & 7);
                gl2lds16(gb + (size_t)(col0 + r) * DD + c * 8, buf + (l * 4 + w) * 512);
            }
        } else {
#pragma unroll
            for (int l = 0; l < 4; ++l) {
                int id = l * 256 + tid;
                int r = id >> 4, c = id & 15, p = c ^ (r & 7);
                const float4* src = reinterpret_cast<const float4*>(xb + (size_t)(col0 + r) * DD + c * 8);
                float4 v0 = src[0], v1 = src[1];
                short8 pk;
                pk[0] = (short)f2bf(v0.x); pk[1] = (short)f2bf(v0.y);
                pk[2] = (short)f2bf(v0.z); pk[3] = (short)f2bf(v0.w);
                pk[4] = (short)f2bf(v1.x); pk[5] = (short)f2bf(v1.y);
                pk[6] = (short)f2bf(v1.z); pk[7] = (short)f2bf(v1.w);
                *reinterpret_cast<short8*>(buf + r * DD + p * 8) = pk;
            }
        }
    }
    __syncthreads();

    // per-(lane, rg, reg) sorted top-4 packed keys. Lossless for global top-3.
    unsigned int tk[2][4][4];
#pragma unroll
    for (int rg = 0; rg < 2; ++rg)
#pragma unroll
        for (int i = 0; i < 4; ++i)
#pragma unroll
            for (int q = 0; q < 4; ++q) tk[rg][i][q] = 0xFFFFFFFFu;

    for (int ct = 0; ct < tiles; ++ct) {
        unsigned short* cur = btile + (size_t)(ct & 1) * CN * DD;
        unsigned short* nxt = btile + (size_t)((ct + 1) & 1) * CN * DD;
        int colbase = col0 + ct * CN;

        if (ct + 1 < tiles) {
            int cb = colbase + CN;
            if constexpr (PRE) {
#pragma unroll
                for (int l = 0; l < 4; ++l) {
                    int f = (l * 4 + w) * 64 + lane;
                    int r = f >> 4, p = f & 15;
                    int c = p ^ (r & 7);
                    gl2lds16(gb + (size_t)(cb + r) * DD + c * 8, nxt + (l * 4 + w) * 512);
                }
            } else {
#pragma unroll
                for (int l = 0; l < 4; ++l) {
                    int id = l * 256 + tid;
                    int r = id >> 4, c = id & 15, p = c ^ (r & 7);
                    const float4* src = reinterpret_cast<const float4*>(xb + (size_t)(cb + r) * DD + c * 8);
                    float4 v0 = src[0], v1 = src[1];
                    short8 pk;
                    pk[0] = (short)f2bf(v0.x); pk[1] = (short)f2bf(v0.y);
                    pk[2] = (short)f2bf(v0.z); pk[3] = (short)f2bf(v0.w);
                    pk[4] = (short)f2bf(v1.x); pk[5] = (short)f2bf(v1.y);
                    pk[6] = (short)f2bf(v1.z); pk[7] = (short)f2bf(v1.w);
                    *reinterpret_cast<short8*>(nxt + r * DD + p * 8) = pk;
                }
            }
        }

        float sqb[4];
#pragma unroll
        for (int cc = 0; cc < 4; ++cc)
            sqb[cc] = sqv[(size_t)b * NN + colbase + cc * 16 + m] + 1024.0f;

        // ---- 32 MFMAs from 16 b128 reads ----
        float4v acc[2][4];
#pragma unroll
        for (int rg = 0; rg < 2; ++rg)
#pragma unroll
            for (int cc = 0; cc < 4; ++cc) acc[rg][cc] = (float4v){0.f, 0.f, 0.f, 0.f};
#pragma unroll
        for (int kc = 0; kc < 4; ++kc) {
            short8 bfrag[4];
#pragma unroll
            for (int cc = 0; cc < 4; ++cc) {
                int rl = cc * 16 + m;
                int p = (kc * 4 + quad) ^ (m & 7);
                bfrag[cc] = *reinterpret_cast<const short8*>(cur + rl * DD + p * 8);
            }
#pragma unroll
            for (int rg = 0; rg < 2; ++rg)
#pragma unroll
                for (int cc = 0; cc < 4; ++cc)
                    acc[rg][cc] = __builtin_amdgcn_mfma_f32_16x16x32_bf16(
                        afrag[rg][kc], bfrag[cc], acc[rg][cc], 0, 0, 0);
        }

        // ---- branchless selection ----
#pragma unroll
        for (int cc = 0; cc < 4; ++cc) {
            unsigned int col = (unsigned int)(colbase + cc * 16 + m);
#pragma unroll
            for (int rg = 0; rg < 2; ++rg)
#pragma unroll
                for (int reg = 0; reg < 4; ++reg) {
                    float scb = fmaf(-2.f, acc[rg][cc][reg], sqb[cc]);   // 1024 + d2 - sqr > 0
                    unsigned int key = (__builtin_bit_cast(unsigned int, scb) & 0xFFFFF800u) | col;
                    unsigned int n;
                    n = umn(tk[rg][reg][0], key); key = umx(tk[rg][reg][0], key); tk[rg][reg][0] = n;
                    n = umn(tk[rg][reg][1], key); key = umx(tk[rg][reg][1], key); tk[rg][reg][1] = n;
                    n = umn(tk[rg][reg][2], key); key = umx(tk[rg][reg][2], key); tk[rg][reg][2] = n;
                    tk[rg][reg][3] = umn(tk[rg][reg][3], key);
                }
        }

        __syncthreads();   // drains stage(ct+1); all waves done reading cur
    }

    // ---- in-register merge over the 16 m-lanes -> row top-8; write to global ----
#pragma unroll
    for (int rg = 0; rg < 2; ++rg)
#pragma unroll
        for (int reg = 0; reg < 4; ++reg) {
            unsigned int e[8];
#pragma unroll
            for (int j = 0; j < 4; ++j) e[j] = tk[rg][reg][j];
#pragma unroll
            for (int j = 4; j < 8; ++j) e[j] = 0xFFFFFFFFu;
#pragma unroll
            for (int st = 0; st < 4; ++st) {
                int mask = 1 << st;
                unsigned int rv[8];
#pragma unroll
                for (int j = 0; j < 8; ++j)
                    rv[j] = (unsigned int)__shfl_xor((int)e[7 - j], mask, 64);
#pragma unroll
                for (int j = 0; j < 8; ++j) e[j] = umn(e[j], rv[j]);
                CSU(e[0], e[4]); CSU(e[1], e[5]); CSU(e[2], e[6]); CSU(e[3], e[7]);
                CSU(e[0], e[2]); CSU(e[1], e[3]); CSU(e[4], e[6]); CSU(e[5], e[7]);
                CSU(e[0], e[1]); CSU(e[2], e[3]); CSU(e[4], e[5]); CSU(e[6], e[7]);
            }
            if (m == 0) {
                int row = row0 + 32 * w + rg * 16 + quad * 4 + reg;
                unsigned int* dst = top8 + ((size_t)(b * NN + row) * halves + h) * 8;
#pragma unroll
                for (int j = 0; j < 8; ++j) dst[j] = e[j];
            }
        }
}

// Finish: per row, refine 8*halves candidates in fp64, exact top-3, blend, store.
__global__ __launch_bounds__(256) void finish_kernel(const float* __restrict__ x,
        const unsigned int* __restrict__ top8, const float* __restrict__ strength,
        float* __restrict__ out, int halves) {
    __shared__ double refd[32 * 16];
    __shared__ int cidx[32 * 16];
    __shared__ int best3[32 * 3];

    const int tid = threadIdx.x;
    const int r = tid >> 3;          // 0..31 row slot
    const int t8 = tid & 7;
    const int R = blockIdx.x * 32 + r;    // flat row over B*N
    const int b = R >> 11;
    const int n = R & (NN - 1);
    const float* __restrict__ xb = x + (size_t)b * NN * DD;
    const int ncand = 8 * halves;

    const unsigned int* keys = top8 + (size_t)R * ncand;
    const int npt = halves;          // candidates per thread (1 or 2)
#pragma unroll 2
    for (int t = 0; t < npt; ++t) {
        int j = t8 * npt + t;
        int ix = (int)(keys[j] & 0x7FFu);
        const float* pc = xb + (size_t)ix * DD;
        const float* pr = xb + (size_t)n * DD;
        double a = 0.0;
#pragma unroll 4
        for (int d4 = 0; d4 < 32; ++d4) {
            float4 wv = *reinterpret_cast<const float4*>(pr + d4 * 4);
            float4 v = *reinterpret_cast<const float4*>(pc + d4 * 4);
            double d;
            d = (double)wv.x - (double)v.x; a += d * d;
            d = (double)wv.y - (double)v.y; a += d * d;
            d = (double)wv.z - (double)v.z; a += d * d;
            d = (double)wv.w - (double)v.w; a += d * d;
        }
        refd[r * 16 + j] = (ix == n) ? DBL_MAX : a;
        cidx[r * 16 + j] = ix;
    }
    __syncthreads();

    if (tid < 32) {
        int rr = tid;
        double b0 = DBL_MAX, b1 = DBL_MAX, b2 = DBL_MAX;
        int i0 = 0x7fffffff, i1 = 0x7fffffff, i2 = 0x7fffffff;
        for (int e = 0; e < ncand; ++e) {
            double dv = refd[rr * 16 + e];
            int ix = cidx[rr * 16 + e];
            if (dv < b2 || (dv == b2 && ix < i2)) {
                b2 = dv; i2 = ix;
                if (b1 > b2 || (b1 == b2 && i1 > i2)) { double td = b1; b1 = b2; b2 = td; int tn = i1; i1 = i2; i2 = tn; }
                if (b0 > b1 || (b0 == b1 && i0 > i1)) { double td = b0; b0 = b1; b1 = td; int tn = i0; i0 = i1; i1 = tn; }
            }
        }
        best3[rr * 3 + 0] = i0; best3[rr * 3 + 1] = i1; best3[rr * 3 + 2] = i2;
    }
    __syncthreads();

    {
        float s = fminf(fmaxf(strength[0], 0.f), 1.f);
        const float* pa = xb + (size_t)n * DD + t8 * 16;
        const float* p1 = xb + (size_t)best3[r * 3 + 0] * DD + t8 * 16;
        const float* p2 = xb + (size_t)best3[r * 3 + 1] * DD + t8 * 16;
        const float* p3 = xb + (size_t)best3[r * 3 + 2] * DD + t8 * 16;
        float* po = out + (size_t)R * DD + t8 * 16;
#pragma unroll
        for (int l = 0; l < 4; ++l) {
            float4 a  = *reinterpret_cast<const float4*>(pa + l * 4);
            float4 n1 = *reinterpret_cast<const float4*>(p1 + l * 4);
            float4 n2 = *reinterpret_cast<const float4*>(p2 + l * 4);
            float4 n3 = *reinterpret_cast<const float4*>(p3 + l * 4);
            float4 o;
            o.x = (1.f - s) * a.x + s * ((n1.x + n2.x + n3.x) / 3.f);
            o.y = (1.f - s) * a.y + s * ((n1.y + n2.y + n3.y) / 3.f);
            o.z = (1.f - s) * a.z + s * ((n1.z + n2.z + n3.z) / 3.f);
            o.w = (1.f - s) * a.w + s * ((n1.w + n2.w + n3.w) / 3.f);
            *reinterpret_cast<float4*>(po + l * 4) = o;
        }
    }
}

extern "C" void kernel_launch(void* const* d_in, const int* in_sizes, int n_in,
                              void* d_out, int out_size, void* d_ws, size_t ws_size,
                              hipStream_t stream) {
    const float* x = (const float*)d_in[0];
    const float* strength = (const float*)d_in[1];
    float* out = (float*)d_out;

    const size_t SQ_B = 256 * 1024;
    const size_t BF_B = (size_t)BB * NN * DD * 2;        // 16 MB
    float* sq = (float*)d_ws;

    const size_t need_pre2 = SQ_B + BF_B + (size_t)BB * NN * 2 * 8 * 4;  // ~20.5 MB
    const size_t need_pre1 = SQ_B + BF_B + (size_t)BB * NN * 1 * 8 * 4;
    const size_t need_raw2 = SQ_B + (size_t)BB * NN * 2 * 8 * 4;         // ~4.4 MB

    if (ws_size >= need_pre2) {
        unsigned short* xb16 = (unsigned short*)((char*)d_ws + SQ_B);
        unsigned int* top8 = (unsigned int*)((char*)d_ws + SQ_B + BF_B);
        prep_kernel<<<dim3((BB * NN * 4) / 256), 256, 0, stream>>>(x, xb16, sq);
        knn_main<true><<<dim3(BB, NN / RM, 2), 256, 0, stream>>>(x, xb16, sq, top8, 2);
        finish_kernel<<<dim3(BB * NN / 32), 256, 0, stream>>>(x, top8, strength, out, 2);
    } else if (ws_size >= need_pre1) {
        unsigned short* xb16 = (unsigned short*)((char*)d_ws + SQ_B);
        unsigned int* top8 = (unsigned int*)((char*)d_ws + SQ_B + BF_B);
        prep_kernel<<<dim3((BB * NN * 4) / 256), 256, 0, stream>>>(x, xb16, sq);
        knn_main<true><<<dim3(BB, NN / RM, 1), 256, 0, stream>>>(x, xb16, sq, top8, 1);
        finish_kernel<<<dim3(BB * NN / 32), 256, 0, stream>>>(x, top8, strength, out, 1);
    } else if (ws_size >= need_raw2) {
        unsigned int* top8 = (unsigned int*)((char*)d_ws + SQ_B);
        sq_kernel<<<dim3((BB * NN * 4) / 256), 256, 0, stream>>>(x, sq);
        knn_main<false><<<dim3(BB, NN / RM, 2), 256, 0, stream>>>(x, nullptr, sq, top8, 2);
        finish_kernel<<<dim3(BB * NN / 32), 256, 0, stream>>>(x, top8, strength, out, 2);
    } else {
        unsigned int* top8 = (unsigned int*)((char*)d_ws + SQ_B);
        sq_kernel<<<dim3((BB * NN * 4) / 256), 256, 0, stream>>>(x, sq);
        knn_main<false><<<dim3(BB, NN / RM, 1), 256, 0, stream>>>(x, nullptr, sq, top8, 1);
        finish_kernel<<<dim3(BB * NN / 32), 256, 0, stream>>>(x, top8, strength, out, 1);
    }
}

// Round 8
// 204.665 us; speedup vs baseline: 1.2508x; 1.2508x over previous
//
#include <hip/hip_runtime.h>
#include <cfloat>

#define BB 32
#define NN 2048
#define DD 128
#define RM 128    // rows per block (4 waves x 32 rows/wave)
#define CN 64     // cols per tile

typedef __attribute__((ext_vector_type(8))) short short8;
typedef __attribute__((ext_vector_type(4))) float float4v;

__device__ __forceinline__ unsigned short f2bf(float f) {
    unsigned int u = __builtin_bit_cast(unsigned int, f);
    u += 0x7FFFu + ((u >> 16) & 1u);   // RNE
    return (unsigned short)(u >> 16);
}

__device__ __forceinline__ unsigned int umn(unsigned int a, unsigned int b) { return a < b ? a : b; }
__device__ __forceinline__ unsigned int umx(unsigned int a, unsigned int b) { return a > b ? a : b; }
#define CSU(a, b) { unsigned int _lo = umn(a, b), _hi = umx(a, b); (a) = _lo; (b) = _hi; }

// async global->LDS, 16B per lane. LDS dest is wave-uniform base + lane*16.
__device__ __forceinline__ void gl2lds16(const unsigned short* g, unsigned short* l) {
    __builtin_amdgcn_global_load_lds(
        (const __attribute__((address_space(1))) void*)g,
        (__attribute__((address_space(3))) void*)l, 16, 0, 0);
}

// fused: sq = sum(x^2) per row, and bf16 copy of x into workspace
__global__ __launch_bounds__(256) void prep_kernel(const float* __restrict__ x,
        unsigned short* __restrict__ xb16, float* __restrict__ sq) {
    int t = blockIdx.x * 256 + threadIdx.x;
    int row = t >> 2;
    int q = t & 3;
    const float4* xp = reinterpret_cast<const float4*>(x + (size_t)row * DD + q * 32);
    unsigned short* op = xb16 + (size_t)row * DD + q * 32;
    float acc = 0.f;
#pragma unroll
    for (int i = 0; i < 4; ++i) {
        float4 v0 = xp[2 * i], v1 = xp[2 * i + 1];
        acc += v0.x * v0.x + v0.y * v0.y + v0.z * v0.z + v0.w * v0.w;
        acc += v1.x * v1.x + v1.y * v1.y + v1.z * v1.z + v1.w * v1.w;
        short8 pk;
        pk[0] = (short)f2bf(v0.x); pk[1] = (short)f2bf(v0.y);
        pk[2] = (short)f2bf(v0.z); pk[3] = (short)f2bf(v0.w);
        pk[4] = (short)f2bf(v1.x); pk[5] = (short)f2bf(v1.y);
        pk[6] = (short)f2bf(v1.z); pk[7] = (short)f2bf(v1.w);
        *reinterpret_cast<short8*>(op + i * 8) = pk;
    }
    acc += __shfl_xor(acc, 1);
    acc += __shfl_xor(acc, 2);
    if (q == 0) sq[row] = acc;
}

__global__ __launch_bounds__(256) void sq_kernel(const float* __restrict__ x,
                                                 float* __restrict__ sq) {
    int t = blockIdx.x * 256 + threadIdx.x;
    int row = t >> 2;
    int q = t & 3;
    const float4* xp = reinterpret_cast<const float4*>(x + (size_t)row * DD + q * 32);
    float acc = 0.f;
#pragma unroll
    for (int i = 0; i < 8; ++i) {
        float4 v = xp[i];
        acc += v.x * v.x + v.y * v.y + v.z * v.z + v.w * v.w;
    }
    acc += __shfl_xor(acc, 1);
    acc += __shfl_xor(acc, 2);
    if (q == 0) sq[row] = acc;
}

// Main: per (batch, row-block of 128, column-half) -> per-row top-8 packed keys.
// B tile layout: row r (0..63), 16 chunks of 8 bf16; chunk c at pos c^(r&7).
template<bool PRE>
__global__ __launch_bounds__(256, 4) void knn_main(const float* __restrict__ x,
        const unsigned short* __restrict__ xb16g,
        const float* __restrict__ sqv,
        unsigned int* __restrict__ top8, int halves) {
    __shared__ __align__(16) unsigned short btile[2 * CN * DD]; // 32 KB dbuf => 4 blocks/CU

    const int b = blockIdx.x;            // flat%8 = b%8: batch pinned to an XCD
    const int row0 = blockIdx.y * RM;
    const int h = blockIdx.z;
    const int colspan = NN / halves;
    const int col0 = h * colspan;
    const int tiles = colspan / CN;
    const int tid = threadIdx.x;
    const int w = tid >> 6;
    const int lane = tid & 63;
    const int m = lane & 15;
    const int quad = lane >> 4;
    const float* __restrict__ xb = x + (size_t)b * NN * DD;
    const unsigned short* __restrict__ gb = PRE ? xb16g + (size_t)b * NN * DD : nullptr;

    // ---- A fragments direct from global: 2 row-groups x 4 k-chunks per lane ----
    short8 afrag[2][4];
    if constexpr (PRE) {
#pragma unroll
        for (int rg = 0; rg < 2; ++rg)
#pragma unroll
            for (int kc = 0; kc < 4; ++kc)
                afrag[rg][kc] = *reinterpret_cast<const short8*>(
                    gb + (size_t)(row0 + 32 * w + rg * 16 + m) * DD + kc * 32 + quad * 8);
    } else {
#pragma unroll
        for (int rg = 0; rg < 2; ++rg)
#pragma unroll
            for (int kc = 0; kc < 4; ++kc) {
                const float4* src = reinterpret_cast<const float4*>(
                    xb + (size_t)(row0 + 32 * w + rg * 16 + m) * DD + kc * 32 + quad * 8);
                float4 v0 = src[0], v1 = src[1];
                short8 pk;
                pk[0] = (short)f2bf(v0.x); pk[1] = (short)f2bf(v0.y);
                pk[2] = (short)f2bf(v0.z); pk[3] = (short)f2bf(v0.w);
                pk[4] = (short)f2bf(v1.x); pk[5] = (short)f2bf(v1.y);
                pk[6] = (short)f2bf(v1.z); pk[7] = (short)f2bf(v1.w);
                afrag[rg][kc] = pk;
            }
    }

    // ---- stage tile 0 ----
    {
        unsigned short* buf = btile;
        if constexpr (PRE) {
#pragma unroll
            for (int l = 0; l < 4; ++l) {
                int f = (l * 4 + w) * 64 + lane;
                int r = f >> 4, p = f & 15;
                int c = p ^ (r & 7);
                gl2lds16(gb + (size_t)(col0 + r) * DD + c * 8, buf + (l * 4 + w) * 512);
            }
        } else {
#pragma unroll
            for (int l = 0; l < 4; ++l) {
                int id = l * 256 + tid;
                int r = id >> 4, c = id & 15, p = c ^ (r & 7);
                const float4* src = reinterpret_cast<const float4*>(xb + (size_t)(col0 + r) * DD + c * 8);
                float4 v0 = src[0], v1 = src[1];
                short8 pk;
                pk[0] = (short)f2bf(v0.x); pk[1] = (short)f2bf(v0.y);
                pk[2] = (short)f2bf(v0.z); pk[3] = (short)f2bf(v0.w);
                pk[4] = (short)f2bf(v1.x); pk[5] = (short)f2bf(v1.y);
                pk[6] = (short)f2bf(v1.z); pk[7] = (short)f2bf(v1.w);
                *reinterpret_cast<short8*>(buf + r * DD + p * 8) = pk;
            }
        }
    }
    __syncthreads();

    // per-(lane, rg, reg) sorted top-4 packed keys. Lossless for global top-3.
    unsigned int tk[2][4][4];
#pragma unroll
    for (int rg = 0; rg < 2; ++rg)
#pragma unroll
        for (int i = 0; i < 4; ++i)
#pragma unroll
            for (int q = 0; q < 4; ++q) tk[rg][i][q] = 0xFFFFFFFFu;

    for (int ct = 0; ct < tiles; ++ct) {
        unsigned short* cur = btile + (size_t)(ct & 1) * CN * DD;
        unsigned short* nxt = btile + (size_t)((ct + 1) & 1) * CN * DD;
        int colbase = col0 + ct * CN;

        if (ct + 1 < tiles) {
            int cb = colbase + CN;
            if constexpr (PRE) {
#pragma unroll
                for (int l = 0; l < 4; ++l) {
                    int f = (l * 4 + w) * 64 + lane;
                    int r = f >> 4, p = f & 15;
                    int c = p ^ (r & 7);
                    gl2lds16(gb + (size_t)(cb + r) * DD + c * 8, nxt + (l * 4 + w) * 512);
                }
            } else {
#pragma unroll
                for (int l = 0; l < 4; ++l) {
                    int id = l * 256 + tid;
                    int r = id >> 4, c = id & 15, p = c ^ (r & 7);
                    const float4* src = reinterpret_cast<const float4*>(xb + (size_t)(cb + r) * DD + c * 8);
                    float4 v0 = src[0], v1 = src[1];
                    short8 pk;
                    pk[0] = (short)f2bf(v0.x); pk[1] = (short)f2bf(v0.y);
                    pk[2] = (short)f2bf(v0.z); pk[3] = (short)f2bf(v0.w);
                    pk[4] = (short)f2bf(v1.x); pk[5] = (short)f2bf(v1.y);
                    pk[6] = (short)f2bf(v1.z); pk[7] = (short)f2bf(v1.w);
                    *reinterpret_cast<short8*>(nxt + r * DD + p * 8) = pk;
                }
            }
        }

        float sqb[4];
#pragma unroll
        for (int cc = 0; cc < 4; ++cc)
            sqb[cc] = sqv[(size_t)b * NN + colbase + cc * 16 + m] + 1024.0f;

        // ---- 32 MFMAs from 16 b128 reads ----
        float4v acc[2][4];
#pragma unroll
        for (int rg = 0; rg < 2; ++rg)
#pragma unroll
            for (int cc = 0; cc < 4; ++cc) acc[rg][cc] = (float4v){0.f, 0.f, 0.f, 0.f};
#pragma unroll
        for (int kc = 0; kc < 4; ++kc) {
            short8 bfrag[4];
#pragma unroll
            for (int cc = 0; cc < 4; ++cc) {
                int rl = cc * 16 + m;
                int p = (kc * 4 + quad) ^ (m & 7);
                bfrag[cc] = *reinterpret_cast<const short8*>(cur + rl * DD + p * 8);
            }
#pragma unroll
            for (int rg = 0; rg < 2; ++rg)
#pragma unroll
                for (int cc = 0; cc < 4; ++cc)
                    acc[rg][cc] = __builtin_amdgcn_mfma_f32_16x16x32_bf16(
                        afrag[rg][kc], bfrag[cc], acc[rg][cc], 0, 0, 0);
        }

        // ---- branchless selection ----
#pragma unroll
        for (int cc = 0; cc < 4; ++cc) {
            unsigned int col = (unsigned int)(colbase + cc * 16 + m);
#pragma unroll
            for (int rg = 0; rg < 2; ++rg)
#pragma unroll
                for (int reg = 0; reg < 4; ++reg) {
                    float scb = fmaf(-2.f, acc[rg][cc][reg], sqb[cc]);   // 1024 + d2 - sqr > 0
                    unsigned int key = (__builtin_bit_cast(unsigned int, scb) & 0xFFFFF800u) | col;
                    unsigned int n;
                    n = umn(tk[rg][reg][0], key); key = umx(tk[rg][reg][0], key); tk[rg][reg][0] = n;
                    n = umn(tk[rg][reg][1], key); key = umx(tk[rg][reg][1], key); tk[rg][reg][1] = n;
                    n = umn(tk[rg][reg][2], key); key = umx(tk[rg][reg][2], key); tk[rg][reg][2] = n;
                    tk[rg][reg][3] = umn(tk[rg][reg][3], key);
                }
        }

        __syncthreads();   // drains stage(ct+1); all waves done reading cur
    }

    // ---- in-register merge over the 16 m-lanes -> row top-8; write to global ----
#pragma unroll
    for (int rg = 0; rg < 2; ++rg)
#pragma unroll
        for (int reg = 0; reg < 4; ++reg) {
            unsigned int e[8];
#pragma unroll
            for (int j = 0; j < 4; ++j) e[j] = tk[rg][reg][j];
#pragma unroll
            for (int j = 4; j < 8; ++j) e[j] = 0xFFFFFFFFu;
#pragma unroll
            for (int st = 0; st < 4; ++st) {
                int mask = 1 << st;
                unsigned int rv[8];
#pragma unroll
                for (int j = 0; j < 8; ++j)
                    rv[j] = (unsigned int)__shfl_xor((int)e[7 - j], mask, 64);
#pragma unroll
                for (int j = 0; j < 8; ++j) e[j] = umn(e[j], rv[j]);
                CSU(e[0], e[4]); CSU(e[1], e[5]); CSU(e[2], e[6]); CSU(e[3], e[7]);
                CSU(e[0], e[2]); CSU(e[1], e[3]); CSU(e[4], e[6]); CSU(e[5], e[7]);
                CSU(e[0], e[1]); CSU(e[2], e[3]); CSU(e[4], e[5]); CSU(e[6], e[7]);
            }
            if (m == 0) {
                int row = row0 + 32 * w + rg * 16 + quad * 4 + reg;
                unsigned int* dst = top8 + ((size_t)(b * NN + row) * halves + h) * 8;
#pragma unroll
                for (int j = 0; j < 8; ++j) dst[j] = e[j];
            }
        }
}

// Finish: one WAVE per row. Merge half-top-8s to approx-top-8 by key rank
// (in-register), refine those 8 in fp64 with coalesced 8-lanes-per-candidate
// gathers, exact top-3 by (d2, idx), blend, coalesced float2 store.
template<int HALVES>
__global__ __launch_bounds__(256) void finish_kernel(const float* __restrict__ x,
        const unsigned int* __restrict__ top8, const float* __restrict__ strength,
        float* __restrict__ out) {
    const int tid = threadIdx.x;
    const int w = tid >> 6;          // wave -> row slot (4 rows/block)
    const int lane = tid & 63;
    const int c = lane >> 3;         // candidate group 0..7
    const int l8 = lane & 7;
    const int R = blockIdx.x * 4 + w;
    const int b = R >> 11;
    const int n = R & (NN - 1);
    const float* __restrict__ xb = x + (size_t)b * NN * DD;
    const unsigned int* keys = top8 + (size_t)R * (8 * HALVES);

    unsigned int mykey;
    if constexpr (HALVES == 2) {
        // rank-merge 16 sorted-ish keys -> group c takes rank-c key
        unsigned int key = (lane < 16) ? keys[lane] : 0xFFFFFFFFu;
        int cnt = 0;
#pragma unroll
        for (int s = 0; s < 16; ++s) {
            unsigned int ks = (unsigned int)__shfl((int)key, s, 64);
            cnt += (ks < key) ? 1 : 0;
        }
        mykey = 0xFFFFFFFFu;
#pragma unroll
        for (int s = 0; s < 16; ++s) {
            unsigned int ks = (unsigned int)__shfl((int)key, s, 64);
            int rs = __shfl(cnt, s, 64);
            if (rs == c && s < 16) mykey = ks;
        }
    } else {
        mykey = keys[c];
    }
    const int ix = (int)(mykey & 0x7FFu);

    // coalesced refine: 8 lanes x 16 contiguous floats per candidate row
    const float* pr = xb + (size_t)n * DD + l8 * 16;
    const float* pc = xb + (size_t)ix * DD + l8 * 16;
    double a = 0.0;
#pragma unroll
    for (int l = 0; l < 4; ++l) {
        float4 wv = *reinterpret_cast<const float4*>(pr + l * 4);
        float4 v  = *reinterpret_cast<const float4*>(pc + l * 4);
        double d;
        d = (double)wv.x - (double)v.x; a += d * d;
        d = (double)wv.y - (double)v.y; a += d * d;
        d = (double)wv.z - (double)v.z; a += d * d;
        d = (double)wv.w - (double)v.w; a += d * d;
    }
    a += __shfl_xor(a, 1, 64);
    a += __shfl_xor(a, 2, 64);
    a += __shfl_xor(a, 4, 64);
    if (ix == n) a = DBL_MAX;   // self-exclusion

    // exact top-3 by (d2, idx); uniform across the wave (shfl sources are uniform)
    double b0 = DBL_MAX, b1 = DBL_MAX, b2 = DBL_MAX;
    int i0 = 0x7fffffff, i1 = 0x7fffffff, i2 = 0x7fffffff;
#pragma unroll
    for (int e = 0; e < 8; ++e) {
        double dv = __shfl(a, e * 8, 64);
        int iv = __shfl(ix, e * 8, 64);
        if (dv < b2 || (dv == b2 && iv < i2)) {
            b2 = dv; i2 = iv;
            if (b1 > b2 || (b1 == b2 && i1 > i2)) { double td = b1; b1 = b2; b2 = td; int tn = i1; i1 = i2; i2 = tn; }
            if (b0 > b1 || (b0 == b1 && i0 > i1)) { double td = b0; b0 = b1; b1 = td; int tn = i0; i0 = i1; i1 = tn; }
        }
    }

    // blend + coalesced store: 64 lanes x 2 floats = 128 dims
    float s = fminf(fmaxf(strength[0], 0.f), 1.f);
    float2 aa = *reinterpret_cast<const float2*>(xb + (size_t)n * DD + lane * 2);
    float2 n1 = *reinterpret_cast<const float2*>(xb + (size_t)i0 * DD + lane * 2);
    float2 n2 = *reinterpret_cast<const float2*>(xb + (size_t)i1 * DD + lane * 2);
    float2 n3 = *reinterpret_cast<const float2*>(xb + (size_t)i2 * DD + lane * 2);
    float2 o;
    o.x = (1.f - s) * aa.x + s * ((n1.x + n2.x + n3.x) / 3.f);
    o.y = (1.f - s) * aa.y + s * ((n1.y + n2.y + n3.y) / 3.f);
    *reinterpret_cast<float2*>(out + (size_t)R * DD + lane * 2) = o;
}

extern "C" void kernel_launch(void* const* d_in, const int* in_sizes, int n_in,
                              void* d_out, int out_size, void* d_ws, size_t ws_size,
                              hipStream_t stream) {
    const float* x = (const float*)d_in[0];
    const float* strength = (const float*)d_in[1];
    float* out = (float*)d_out;

    const size_t SQ_B = 256 * 1024;
    const size_t BF_B = (size_t)BB * NN * DD * 2;        // 16 MB
    float* sq = (float*)d_ws;

    const size_t need_pre2 = SQ_B + BF_B + (size_t)BB * NN * 2 * 8 * 4;  // ~20.5 MB
    const size_t need_pre1 = SQ_B + BF_B + (size_t)BB * NN * 1 * 8 * 4;
    const size_t need_raw2 = SQ_B + (size_t)BB * NN * 2 * 8 * 4;         // ~4.4 MB

    if (ws_size >= need_pre2) {
        unsigned short* xb16 = (unsigned short*)((char*)d_ws + SQ_B);
        unsigned int* top8 = (unsigned int*)((char*)d_ws + SQ_B + BF_B);
        prep_kernel<<<dim3((BB * NN * 4) / 256), 256, 0, stream>>>(x, xb16, sq);
        knn_main<true><<<dim3(BB, NN / RM, 2), 256, 0, stream>>>(x, xb16, sq, top8, 2);
        finish_kernel<2><<<dim3(BB * NN / 4), 256, 0, stream>>>(x, top8, strength, out);
    } else if (ws_size >= need_pre1) {
        unsigned short* xb16 = (unsigned short*)((char*)d_ws + SQ_B);
        unsigned int* top8 = (unsigned int*)((char*)d_ws + SQ_B + BF_B);
        prep_kernel<<<dim3((BB * NN * 4) / 256), 256, 0, stream>>>(x, xb16, sq);
        knn_main<true><<<dim3(BB, NN / RM, 1), 256, 0, stream>>>(x, xb16, sq, top8, 1);
        finish_kernel<1><<<dim3(BB * NN / 4), 256, 0, stream>>>(x, top8, strength, out);
    } else if (ws_size >= need_raw2) {
        unsigned int* top8 = (unsigned int*)((char*)d_ws + SQ_B);
        sq_kernel<<<dim3((BB * NN * 4) / 256), 256, 0, stream>>>(x, sq);
        knn_main<false><<<dim3(BB, NN / RM, 2), 256, 0, stream>>>(x, nullptr, sq, top8, 2);
        finish_kernel<2><<<dim3(BB * NN / 4), 256, 0, stream>>>(x, top8, strength, out);
    } else {
        unsigned int* top8 = (unsigned int*)((char*)d_ws + SQ_B);
        sq_kernel<<<dim3((BB * NN * 4) / 256), 256, 0, stream>>>(x, sq);
        knn_main<false><<<dim3(BB, NN / RM, 1), 256, 0, stream>>>(x, nullptr, sq, top8, 1);
        finish_kernel<1><<<dim3(BB * NN / 4), 256, 0, stream>>>(x, top8, strength, out);
    }
}